// Round 6
// baseline (390.842 us; speedup 1.0000x reference)
//
#include <hip/hip_runtime.h>
#include <math.h>

#define CH 96
#define HH 256
#define WW 256
#define PD 64      // PDIM
#define NBASE 8
#define KK 13
#define HID 32
#define PLANE 65536  // 256*256

typedef float f32x4 __attribute__((ext_vector_type(4)));
typedef short s16x8 __attribute__((ext_vector_type(8)));

__device__ inline ushort f2bf(float f) {
    uint u = __float_as_uint(f);
    u += 0x7fff + ((u >> 16) & 1);   // round-to-nearest-even
    return (ushort)(u >> 16);
}

// ---------------- K1: partial pooled sums (4 partials per (b,c)) ----------------
__global__ __launch_bounds__(256) void pool_kernel(const float* __restrict__ x,
                                                   float* __restrict__ partial) {
    int blk = blockIdx.x;            // ((b*64+c)*4)+q
    int q = blk & 3, c = (blk >> 2) & 63, b = blk >> 8;
    const float4* p4 = (const float4*)(x + (size_t)(b * CH + c) * PLANE) + q * 4096;
    int t = threadIdx.x;
    float s = 0.f;
#pragma unroll
    for (int i = 0; i < 16; ++i) {
        float4 v = p4[t + (i << 8)];
        s += v.x + v.y + v.z + v.w;
    }
#pragma unroll
    for (int off = 32; off; off >>= 1) s += __shfl_down(s, off, 64);
    __shared__ float ls[4];
    if ((t & 63) == 0) ls[t >> 6] = s;
    __syncthreads();
    if (t == 0) partial[blk] = ls[0] + ls[1] + ls[2] + ls[3];
}

// ---------------- K2: tiny MLPs + softmaxes + merged pre-gated 13x13 kernel ----------------
__global__ __launch_bounds__(256) void mlp_kernel(
    const float* __restrict__ partial, const float* __restrict__ lk_bases,
    const float* __restrict__ rw1, const float* __restrict__ rb1,
    const float* __restrict__ rw2, const float* __restrict__ rb2,
    const float* __restrict__ sw1, const float* __restrict__ sb1,
    const float* __restrict__ sw2, const float* __restrict__ sb2,
    const float* __restrict__ gw1, const float* __restrict__ gb1,
    const float* __restrict__ gw2, const float* __restrict__ gb2,
    float* __restrict__ keff) {
    int b = blockIdx.x;
    int t = threadIdx.x;
    __shared__ float pl[64];
    __shared__ float h[3][HID];
    __shared__ float ro[PD * NBASE];
    __shared__ float go[2 * PD];
    __shared__ float rw[PD][NBASE];
    __shared__ float dk_s[PD * 9];
    __shared__ float gl_s[PD], gd_s[PD];

    if (t < 64) {
        const float* pp = &partial[(b * 64 + t) * 4];
        pl[t] = (pp[0] + pp[1] + pp[2] + pp[3]) * (1.f / 65536.f);
    }
    __syncthreads();

    if (t < 96) {
        int m = t >> 5, u = t & 31;
        const float* w1 = (m == 0) ? rw1 : ((m == 1) ? sw1 : gw1);
        const float* b1 = (m == 0) ? rb1 : ((m == 1) ? sb1 : gb1);
        float a = b1[u];
#pragma unroll
        for (int i = 0; i < 64; ++i) a += w1[u * 64 + i] * pl[i];
        h[m][u] = a * 0.5f * (1.f + erff(a * 0.70710678118654752f));
    }
    __syncthreads();

    for (int o = t; o < PD * NBASE; o += 256) {
        float a = rb2[o];
#pragma unroll
        for (int i = 0; i < HID; ++i) a += rw2[o * HID + i] * h[0][i];
        ro[o] = a;
    }
    for (int o = t; o < PD * 9; o += 256) {
        float a = sb2[o];
#pragma unroll
        for (int i = 0; i < HID; ++i) a += sw2[o * HID + i] * h[1][i];
        dk_s[o] = a;
    }
    if (t < 2 * PD) {
        float a = gb2[t];
#pragma unroll
        for (int i = 0; i < HID; ++i) a += gw2[t * HID + i] * h[2][i];
        go[t] = a;
    }
    __syncthreads();

    if (t < 64) {
        float m = -1e30f;
#pragma unroll
        for (int n = 0; n < NBASE; ++n) m = fmaxf(m, ro[t * NBASE + n]);
        float e[NBASE], s = 0.f;
#pragma unroll
        for (int n = 0; n < NBASE; ++n) { e[n] = expf(ro[t * NBASE + n] - m); s += e[n]; }
        float inv = 1.f / s;
#pragma unroll
        for (int n = 0; n < NBASE; ++n) rw[t][n] = e[n] * inv;
        float a0 = go[t], a1 = go[64 + t];
        float mm = fmaxf(a0, a1);
        float e0 = expf(a0 - mm), e1 = expf(a1 - mm);
        float gi = 1.f / (e0 + e1);
        gl_s[t] = e0 * gi;
        gd_s[t] = e1 * gi;
    }
    __syncthreads();

    // keff = gl * (softmax-weighted bases) + gd * pad(dyn 3x3 at center)
    for (int idx = t; idx < 64 * 169; idx += 256) {
        int c = idx / 169;
        int tap = idx - c * 169;
        int dy = tap / 13, dx = tap - dy * 13;
        float a = 0.f;
#pragma unroll
        for (int n = 0; n < NBASE; ++n) a += rw[c][n] * lk_bases[n * 169 + tap];
        a *= gl_s[c];
        if (dy >= 5 && dy < 8 && dx >= 5 && dx < 8)
            a += gd_s[c] * dk_s[c * 9 + (dy - 5) * 3 + (dx - 5)];
        keff[(size_t)(b * 64 + c) * 169 + tap] = a;
    }
}

// ---------------- K3: merged depthwise 13x13, software-pipelined, bf16 output ----------------
// All in-loop memory is LDS (taps staged to LDS too -> no s_load/ds_read lgkmcnt
// mixing). 5-slot VGPR ring of input rows, double-buffered tap row, distance-1
// prefetch covered by 208 FMAs per dy step.
#define TDIM 64
#define TSTR 76      // 64 + 12, multiple of 4 (b128-aligned)
#define TROWS 76

__global__ __launch_bounds__(256) void conv_kernel(
    const float* __restrict__ x, const float* __restrict__ keff,
    float* __restrict__ outp) {
    int tx = blockIdx.x;              // 16 tiles: 4x4 of 64x64
    int wt = tx & 3, ht = tx >> 2;
    int c = blockIdx.y, b = blockIdx.z;
    int h0 = ht * TDIM, w0 = wt * TDIM;
    int t = threadIdx.x;

    __shared__ __align__(16) float tile[TROWS * TSTR];   // 23.1 KB
    __shared__ __align__(16) float kt_lds[13 * 16];      // tap rows, 16-stride

    const float* xp = x + (size_t)(b * CH + c) * PLANE;
    {
        // incremental row/col tracking: 256 = 3*76 + 28
        int rr = t / 76;
        int cc = t - rr * 76;
#pragma unroll
        for (int it = 0; it < 23; ++it) {
            if (it < 22 || t < 144) {     // 5776 - 22*256 = 144
                int gh = h0 - 6 + rr, gw = w0 - 6 + cc;
                float v = 0.f;
                if (gh >= 0 && gh < HH && gw >= 0 && gw < WW) v = xp[gh * WW + gw];
                tile[rr * TSTR + cc] = v;
            }
            cc += 28; rr += 3;
            if (cc >= TSTR) { cc -= TSTR; rr += 1; }
        }
    }
    if (t < 169) {
        int dy = t / 13, dx = t - dy * 13;
        kt_lds[dy * 16 + dx] = keff[(size_t)(b * 64 + c) * 169 + t];
    }
    __syncthreads();

    const int tc4 = 4 * (t & 15);   // col offset (floats); lane stride 16B
    const int rb = 4 * (t >> 4);    // first output row in tile coords

    float acc[4][4] = {{0.f}};
    float xr_[5][16];               // input-row ring
    float kt_[2][16];               // tap-row double buffer

    // prologue: input rows 0..3, tap row 0
#pragma unroll
    for (int p = 0; p < 4; ++p) {
        const float* s = &tile[(rb + p) * TSTR + tc4];
        *(float4*)&xr_[p][0]  = *(const float4*)&s[0];
        *(float4*)&xr_[p][4]  = *(const float4*)&s[4];
        *(float4*)&xr_[p][8]  = *(const float4*)&s[8];
        *(float4*)&xr_[p][12] = *(const float4*)&s[12];
    }
    *(float4*)&kt_[0][0] = *(const float4*)&kt_lds[0];
    *(float4*)&kt_[0][4] = *(const float4*)&kt_lds[4];
    *(float4*)&kt_[0][8] = *(const float4*)&kt_lds[8];
    kt_[0][12] = kt_lds[12];

#pragma unroll
    for (int dy = 0; dy < 13; ++dy) {
        const int cur = dy & 1, nxt = cur ^ 1;
        if (dy < 12) {
            const float* kp = &kt_lds[(dy + 1) * 16];
            *(float4*)&kt_[nxt][0] = *(const float4*)&kp[0];
            *(float4*)&kt_[nxt][4] = *(const float4*)&kp[4];
            *(float4*)&kt_[nxt][8] = *(const float4*)&kp[8];
            kt_[nxt][12] = kp[12];
            const int s4 = (dy + 4) % 5;
            const float* xs = &tile[(rb + dy + 4) * TSTR + tc4];
            *(float4*)&xr_[s4][0]  = *(const float4*)&xs[0];
            *(float4*)&xr_[s4][4]  = *(const float4*)&xs[4];
            *(float4*)&xr_[s4][8]  = *(const float4*)&xs[8];
            *(float4*)&xr_[s4][12] = *(const float4*)&xs[12];
        }
#pragma unroll
        for (int i = 0; i < 4; ++i) {
            const int sl = (dy + i) % 5;
#pragma unroll
            for (int dx = 0; dx < 13; ++dx)
#pragma unroll
                for (int m = 0; m < 4; ++m)
                    acc[i][m] = fmaf(kt_[cur][dx], xr_[sl][dx + m], acc[i][m]);
        }
    }

    // bf16 epilogue into x2 region of this batch
    ushort* fB = (ushort*)(outp + ((size_t)b * CH + 64) * PLANE);
    size_t base = (size_t)c * PLANE + (size_t)(h0 + rb) * WW + (w0 + tc4);
#pragma unroll
    for (int i = 0; i < 4; ++i) {
        uint2 u;
        u.x = (uint)f2bf(acc[i][0]) | ((uint)f2bf(acc[i][1]) << 16);
        u.y = (uint)f2bf(acc[i][2]) | ((uint)f2bf(acc[i][3]) << 16);
        *(uint2*)&fB[base + (size_t)i * WW] = u;
    }
}

// ---------------- K4: pointwise 64x64 via bf16 MFMA + bias + residual ----------------
__global__ __launch_bounds__(256) void pw_kernel(
    const float* __restrict__ x, const float* __restrict__ fw,
    const float* __restrict__ fb, float* outp) {
    int b = blockIdx.y;
    int w = threadIdx.x >> 6;
    int l = threadIdx.x & 63;
    int px0 = blockIdx.x * 256 + w * 64;
    int lr = l & 15;
    int lg = l >> 4;

    const ushort* fBS = (const ushort*)(outp + ((size_t)b * CH + 64) * PLANE);
    const size_t bb = (size_t)b * CH * PLANE;

    // A-frags (W -> bf16), loaded once
    s16x8 wa[4][2];
#pragma unroll
    for (int ot = 0; ot < 4; ++ot)
#pragma unroll
        for (int ks = 0; ks < 2; ++ks) {
            const float* src = fw + (ot * 16 + lr) * 64 + ks * 32 + lg * 8;
            float4 a0 = *(const float4*)(src);
            float4 a1 = *(const float4*)(src + 4);
            s16x8 v;
            v[0] = (short)f2bf(a0.x); v[1] = (short)f2bf(a0.y);
            v[2] = (short)f2bf(a0.z); v[3] = (short)f2bf(a0.w);
            v[4] = (short)f2bf(a1.x); v[5] = (short)f2bf(a1.y);
            v[6] = (short)f2bf(a1.z); v[7] = (short)f2bf(a1.w);
            wa[ot][ks] = v;
        }

#pragma unroll
    for (int pxg = 0; pxg < 4; ++pxg) {
        int px = px0 + pxg * 16 + lr;
        s16x8 vb[2];
#pragma unroll
        for (int ks = 0; ks < 2; ++ks) {
            const ushort* src = fBS + (size_t)(ks * 32 + lg * 8) * PLANE + px;
            s16x8 v;
#pragma unroll
            for (int i = 0; i < 8; ++i) v[i] = (short)src[(size_t)i * PLANE];
            vb[ks] = v;
        }
#pragma unroll
        for (int ot = 0; ot < 4; ++ot) {
            f32x4 acc = {0.f, 0.f, 0.f, 0.f};
            acc = __builtin_amdgcn_mfma_f32_16x16x32_bf16(wa[ot][0], vb[0], acc, 0, 0, 0);
            acc = __builtin_amdgcn_mfma_f32_16x16x32_bf16(wa[ot][1], vb[1], acc, 0, 0, 0);
            float4 fbv = *(const float4*)(fb + ot * 16 + lg * 4);
#pragma unroll
            for (int i = 0; i < 4; ++i) {
                int o = ot * 16 + lg * 4 + i;
                size_t off = bb + (size_t)o * PLANE + px;
                outp[off] = acc[i] + ((const float*)&fbv)[i] + x[off];
            }
        }
    }
}

// ---------------- K5: pass-through copy of channels 64..95 (AFTER pw consumed fB) ----------------
__global__ __launch_bounds__(256) void copy_kernel(const float* __restrict__ x,
                                                   float* __restrict__ outp) {
    size_t i = (size_t)blockIdx.x * 256 + threadIdx.x;  // over 4,194,304 float4
    int b = (int)(i >> 19);                             // 524288 float4 per batch
    size_t off = i & 524287;
    const float4* s = (const float4*)(x + ((size_t)b * CH + 64) * PLANE) + off;
    float4* d = (float4*)(outp + ((size_t)b * CH + 64) * PLANE) + off;
    *d = *s;
}

extern "C" void kernel_launch(void* const* d_in, const int* in_sizes, int n_in,
                              void* d_out, int out_size, void* d_ws, size_t ws_size,
                              hipStream_t stream) {
    const float* x        = (const float*)d_in[0];
    const float* lk_bases = (const float*)d_in[1];
    const float* rw1      = (const float*)d_in[2];
    const float* rb1      = (const float*)d_in[3];
    const float* rw2      = (const float*)d_in[4];
    const float* rb2      = (const float*)d_in[5];
    const float* sw1      = (const float*)d_in[6];
    const float* sb1      = (const float*)d_in[7];
    const float* sw2      = (const float*)d_in[8];
    const float* sb2      = (const float*)d_in[9];
    const float* gw1      = (const float*)d_in[10];
    const float* gb1      = (const float*)d_in[11];
    const float* gw2      = (const float*)d_in[12];
    const float* gb2      = (const float*)d_in[13];
    const float* fw       = (const float*)d_in[14];
    const float* fb       = (const float*)d_in[15];
    float* outp = (float*)d_out;

    float* wsf     = (float*)d_ws;
    float* partial = wsf;            // 2048 floats
    float* keff    = wsf + 2048;     // 8*64*169 = 86528 floats

    pool_kernel<<<dim3(2048), dim3(256), 0, stream>>>(x, partial);
    mlp_kernel<<<dim3(8), dim3(256), 0, stream>>>(partial, lk_bases,
        rw1, rb1, rw2, rb2, sw1, sb1, sw2, sb2, gw1, gb1, gw2, gb2, keff);
    conv_kernel<<<dim3(16, 64, 8), dim3(256), 0, stream>>>(x, keff, outp);
    pw_kernel<<<dim3(256, 8), dim3(256), 0, stream>>>(x, fw, fb, outp);
    copy_kernel<<<dim3(16384), dim3(256), 0, stream>>>(x, outp);
}